// Round 2
// baseline (66.224 us; speedup 1.0000x reference)
//
#include <hip/hip_runtime.h>

// Problem constants (B=8, C=128, H=W=48 -> N=2304)
#define NTOK 2304
#define CC   128
#define BT   128   // block tile (M and N)

typedef __attribute__((ext_vector_type(8))) short bf16x8;
typedef __attribute__((ext_vector_type(4))) float f32x4;

// round-to-nearest-even fp32 -> bf16
__device__ __forceinline__ unsigned f2bf(float f) {
  unsigned int u = __builtin_bit_cast(unsigned int, f);
  u += 0x7FFFu + ((u >> 16) & 1u);
  return (u >> 16) & 0xFFFFu;
}

// Prep: exact fp32 squared norms of every column of x and y.
// Block = 256 threads = 64 columns x 4 C-quarters. Grid (36, 8, 2).
__global__ __launch_bounds__(256) void pwd_prep_norms(
    const float* __restrict__ x, const float* __restrict__ y,
    float* __restrict__ sx, float* __restrict__ sy) {
  __shared__ float part[4][64];
  const int tid = threadIdx.x;
  const int nl = tid & 63;
  const int cq = tid >> 6;
  const int n = blockIdx.x * 64 + nl;
  const int b = blockIdx.y;
  const float* src = blockIdx.z ? y : x;
  const float* p = src + ((size_t)b * CC + cq * 32) * NTOK + n;
  float s = 0.f;
#pragma unroll
  for (int c = 0; c < 32; ++c) {
    float v = p[(size_t)c * NTOK];
    s = fmaf(v, v, s);
  }
  part[cq][nl] = s;
  __syncthreads();
  if (tid < 64) {
    float t = part[0][tid] + part[1][tid] + part[2][tid] + part[3][tid];
    float* dst = blockIdx.z ? sy : sx;
    dst[b * NTOK + blockIdx.x * 64 + tid] = t;
  }
}

// Main: out[b][i][j] = sx[b][i] + sy[b][j] - 2 * sum_c y[b][c][i]*x[b][c][j]
// A (rows i) = y columns, B (cols j) = x columns, staged bf16 K-contiguous in LDS.
// LDS slot swizzle: slot = o ^ (n&15) ^ ((n>>4)&3)  (conflict-free write AND read).
__global__ __launch_bounds__(256, 2) void pwd_gemm(
    const float* __restrict__ x, const float* __restrict__ y,
    const float* __restrict__ sx, const float* __restrict__ sy,
    float* __restrict__ out) {
  __shared__ __attribute__((aligned(16))) char smem[66560];
  char* smA = smem;                       // 128 rows * 256 B (128 bf16, swizzled 16B slots)
  char* smB = smem + 32768;
  float* s_sx = (float*)(smem + 65536);   // 128 floats
  float* s_sy = (float*)(smem + 66048);   // 128 floats
  float* s_tile = (float*)smem;           // epilogue: 128x128 fp32 (reuses smA+smB)

  const int tid = threadIdx.x;

  // XCD-aware bijective swizzle: 2592 blocks = 8 * 324; each XCD gets one
  // batch-contiguous chunk (per-batch inputs 2.4 MB fit the 4 MB XCD L2).
  const int bid = blockIdx.x;
  const int lin = (bid & 7) * 324 + (bid >> 3);
  const int b   = lin / 324;
  const int rem = lin - b * 324;
  const int byy = rem / 18;
  const int bxx = rem - byy * 18;
  const int i0 = byy * BT;   // output rows
  const int j0 = bxx * BT;   // output cols

  // ---------------- staging: global fp32 [k][n] -> LDS bf16 [n][k] ----------
  // thread t: column group g = t&31 (cols 4g..4g+3), k-base kb = (t>>5)*16.
  {
    const int g  = tid & 31;
    const int kb = (tid >> 5) * 16;
    const float* baseA = y + (size_t)b * CC * NTOK + i0 + 4 * g;
    const float* baseB = x + (size_t)b * CC * NTOK + j0 + 4 * g;
#pragma unroll
    for (int h = 0; h < 2; ++h) {
      const int o = (kb >> 3) + h;       // 16B slot index = k>>3
      // ---- A operand (y) ----
      {
        float va[8][4];
#pragma unroll
        for (int kk = 0; kk < 8; ++kk)
          *(float4*)va[kk] = *(const float4*)(baseA + (size_t)(kb + h * 8 + kk) * NTOK);
#pragma unroll
        for (int c = 0; c < 4; ++c) {
          const int n = 4 * g + c;
          uint4 wv;
          wv.x = f2bf(va[0][c]) | (f2bf(va[1][c]) << 16);
          wv.y = f2bf(va[2][c]) | (f2bf(va[3][c]) << 16);
          wv.z = f2bf(va[4][c]) | (f2bf(va[5][c]) << 16);
          wv.w = f2bf(va[6][c]) | (f2bf(va[7][c]) << 16);
          const int slot = o ^ (n & 15) ^ ((n >> 4) & 3);
          *(uint4*)(smA + n * 256 + slot * 16) = wv;
        }
      }
      // ---- B operand (x) ----
      {
        float vb[8][4];
#pragma unroll
        for (int kk = 0; kk < 8; ++kk)
          *(float4*)vb[kk] = *(const float4*)(baseB + (size_t)(kb + h * 8 + kk) * NTOK);
#pragma unroll
        for (int c = 0; c < 4; ++c) {
          const int n = 4 * g + c;
          uint4 wv;
          wv.x = f2bf(vb[0][c]) | (f2bf(vb[1][c]) << 16);
          wv.y = f2bf(vb[2][c]) | (f2bf(vb[3][c]) << 16);
          wv.z = f2bf(vb[4][c]) | (f2bf(vb[5][c]) << 16);
          wv.w = f2bf(vb[6][c]) | (f2bf(vb[7][c]) << 16);
          const int slot = o ^ (n & 15) ^ ((n >> 4) & 3);
          *(uint4*)(smB + n * 256 + slot * 16) = wv;
        }
      }
    }
  }
  if (tid < 128) s_sx[tid] = sx[b * NTOK + i0 + tid];
  else           s_sy[tid - 128] = sy[b * NTOK + j0 + (tid - 128)];
  __syncthreads();

  // ---------------- compute: 4 waves in 2x2, each 64x64 ---------------------
  const int l  = tid & 63;
  const int w  = tid >> 6;
  const int wm = (w >> 1) * 64;
  const int wn = (w & 1) * 64;
  const int lr = l & 15;   // fragment row/col within 16
  const int lg = l >> 4;   // k-group 0..3

  f32x4 acc[4][4] = {};
#pragma unroll
  for (int ks = 0; ks < 4; ++ks) {
    bf16x8 af[4], bfr[4];
    const int o = ks * 4 + lg;           // 16B slot (8 k's)
#pragma unroll
    for (int mf = 0; mf < 4; ++mf) {
      const int n = wm + mf * 16 + lr;
      const int slot = o ^ (n & 15) ^ ((n >> 4) & 3);
      af[mf] = *(const bf16x8*)(smA + n * 256 + slot * 16);
    }
#pragma unroll
    for (int nf = 0; nf < 4; ++nf) {
      const int n = wn + nf * 16 + lr;
      const int slot = o ^ (n & 15) ^ ((n >> 4) & 3);
      bfr[nf] = *(const bf16x8*)(smB + n * 256 + slot * 16);
    }
#pragma unroll
    for (int mf = 0; mf < 4; ++mf)
#pragma unroll
      for (int nf = 0; nf < 4; ++nf)
        acc[mf][nf] = __builtin_amdgcn_mfma_f32_16x16x32_bf16(
            af[mf], bfr[nf], acc[mf][nf], 0, 0, 0);
  }

  // ---------------- epilogue: P = sx[i] + sy[j] - 2*zz, via LDS transpose ---
  __syncthreads();   // operand LDS dead; safe to overwrite
  // write P[row][col] at col ^ (row-bit-2 << 4) to spread banks
#pragma unroll
  for (int mf = 0; mf < 4; ++mf) {
#pragma unroll
    for (int nf = 0; nf < 4; ++nf) {
      const int col = wn + nf * 16 + lr;
      const float syv = s_sy[col];
#pragma unroll
      for (int r = 0; r < 4; ++r) {
        const int row = wm + mf * 16 + lg * 4 + r;  // C/D layout (m89)
        const int cs = col ^ (((row >> 2) & 1) << 4);
        s_tile[row * 128 + cs] = s_sx[row] + syv - 2.0f * acc[mf][nf][r];
      }
    }
  }
  __syncthreads();
  // stream out: thread t handles rows (t>>5)+8*it, float4 col-group t&31
  {
    const int c4 = tid & 31;
    const int r0 = tid >> 5;
#pragma unroll
    for (int it = 0; it < 16; ++it) {
      const int row = r0 + it * 8;
      const int c4s = c4 ^ (((row >> 2) & 1) << 2);   // matches bit-4 col flip
      float4 v = *(const float4*)(s_tile + row * 128 + c4s * 4);
      *(float4*)(out + ((size_t)b * NTOK + (i0 + row)) * NTOK + j0 + c4 * 4) = v;
    }
  }
}

extern "C" void kernel_launch(void* const* d_in, const int* in_sizes, int n_in,
                              void* d_out, int out_size, void* d_ws, size_t ws_size,
                              hipStream_t stream) {
  (void)in_sizes; (void)n_in; (void)out_size; (void)ws_size;
  const float* x = (const float*)d_in[0];
  const float* y = (const float*)d_in[1];
  float* out = (float*)d_out;
  float* sx = (float*)d_ws;              // 8*2304 fp32
  float* sy = sx + 8 * NTOK;             // 8*2304 fp32 (total 147,456 B of ws)

  dim3 gp(NTOK / 64, 8, 2);
  pwd_prep_norms<<<gp, dim3(256), 0, stream>>>(x, y, sx, sy);

  dim3 gg(18 * 18 * 8);
  pwd_gemm<<<gg, dim3(256), 0, stream>>>(x, y, sx, sy, out);
}

// Round 5
// 56.418 us; speedup vs baseline: 1.1738x; 1.1738x over previous
//
#include <hip/hip_runtime.h>

// Problem constants (B=8, C=128, H=W=48 -> N=2304)
#define NTOK 2304
#define CC   128

typedef __attribute__((ext_vector_type(8))) short bf16x8;
typedef __attribute__((ext_vector_type(4))) float f32x4;

// round-to-nearest-even fp32 -> bf16
__device__ __forceinline__ unsigned f2bf(float f) {
  unsigned int u = __builtin_bit_cast(unsigned int, f);
  u += 0x7FFFu + ((u >> 16) & 1u);
  return (u >> 16) & 0xFFFFu;
}
__device__ __forceinline__ unsigned pk2(float a, float b) {
  return f2bf(a) | (f2bf(b) << 16);
}

// Prep: exact fp32 squared norms. sx from x, sy from y (NOTE the reference
// quirk: out[b][i][j] = ||x_i||^2 + ||y_j||^2 - 2*y_i.x_j -- row i uses x's
// norm, col j uses y's norm, so these CANNOT be fused into the gemm's panels).
__global__ __launch_bounds__(256) void pwd_prep_norms(
    const float* __restrict__ x, const float* __restrict__ y,
    float* __restrict__ sx, float* __restrict__ sy) {
  __shared__ float part[4][64];
  const int tid = threadIdx.x;
  const int nl = tid & 63;
  const int cq = tid >> 6;
  const int n = blockIdx.x * 64 + nl;
  const int b = blockIdx.y;
  const float* src = blockIdx.z ? y : x;
  const float* p = src + ((size_t)b * CC + cq * 32) * NTOK + n;
  float s = 0.f;
#pragma unroll
  for (int c = 0; c < 32; ++c) {
    float v = p[(size_t)c * NTOK];
    s = fmaf(v, v, s);
  }
  part[cq][nl] = s;
  __syncthreads();
  if (tid < 64) {
    float t = part[0][tid] + part[1][tid] + part[2][tid] + part[3][tid];
    float* dst = blockIdx.z ? sy : sx;
    dst[b * NTOK + blockIdx.x * 64 + tid] = t;
  }
}

// Main: out[b][i][j] = sx[i] + sy[j] - 2 * (y_i . x_j)
// A (rows i) = y columns @ i0, B (cols j) = x columns @ j0, staged bf16
// K-contiguous in LDS, slot swizzle slot = (k>>3) ^ (n&15) ^ ((n>>4)&3)
// (conflict-free for both ds_write_b128 and ds_read_b128 lane patterns).
// 512 threads, 8 waves in 2x4 (wave tile 64x32), 2 blocks/CU -> 4 waves/SIMD.
__global__ __launch_bounds__(512, 4) void pwd_gemm(
    const float* __restrict__ x, const float* __restrict__ y,
    const float* __restrict__ sx, const float* __restrict__ sy,
    float* __restrict__ out) {
  __shared__ __attribute__((aligned(16))) char smem[66560];
  char*  smA  = smem;                     // 128 rows * 256 B (128 bf16, swizzled)
  char*  smB  = smem + 32768;
  float* s_sx = (float*)(smem + 65536);   // 128 floats
  float* s_sy = (float*)(smem + 66048);   // 128 floats

  const int tid = threadIdx.x;

  // XCD-aware swizzle: grid 2592 = 8*324; bid%8 (the XCD round-robin slot)
  // selects the batch -> each XCD works one batch; its 2.4 MB inputs fit L2.
  const int bid = blockIdx.x;
  const int b   = bid & 7;
  const int rem = bid >> 3;            // 0..323
  const int byy = rem / 18;
  const int bxx = rem - byy * 18;
  const int i0 = byy * 128;            // output rows
  const int j0 = bxx * 128;            // output cols

  const int g  = tid & 31;             // column group: cols 4g..4g+3
  const int q  = tid >> 5;             // k-block 0..15 -> k in [8q, 8q+8)
  const int k0 = q * 8;
  const int w  = tid >> 6;             // wave 0..7

  // ---------------- stage A (y -> smA) --------------------------------------
  {
    const float* base = y + ((size_t)b * CC + k0) * NTOK + i0 + 4 * g;
    float v[8][4];
#pragma unroll
    for (int kk = 0; kk < 8; ++kk)
      *(float4*)v[kk] = *(const float4*)(base + (size_t)kk * NTOK);
#pragma unroll
    for (int c = 0; c < 4; ++c) {
      const int n = 4 * g + c;
      uint4 wv;
      wv.x = pk2(v[0][c], v[1][c]);
      wv.y = pk2(v[2][c], v[3][c]);
      wv.z = pk2(v[4][c], v[5][c]);
      wv.w = pk2(v[6][c], v[7][c]);
      const int slot = q ^ (n & 15) ^ ((n >> 4) & 3);
      *(uint4*)(smA + n * 256 + slot * 16) = wv;
    }
  }
  // ---------------- stage B (x -> smB) --------------------------------------
  {
    const float* base = x + ((size_t)b * CC + k0) * NTOK + j0 + 4 * g;
    float v[8][4];
#pragma unroll
    for (int kk = 0; kk < 8; ++kk)
      *(float4*)v[kk] = *(const float4*)(base + (size_t)kk * NTOK);
#pragma unroll
    for (int c = 0; c < 4; ++c) {
      const int n = 4 * g + c;
      uint4 wv;
      wv.x = pk2(v[0][c], v[1][c]);
      wv.y = pk2(v[2][c], v[3][c]);
      wv.z = pk2(v[4][c], v[5][c]);
      wv.w = pk2(v[6][c], v[7][c]);
      const int slot = q ^ (n & 15) ^ ((n >> 4) & 3);
      *(uint4*)(smB + n * 256 + slot * 16) = wv;
    }
  }
  if (tid < 128)       s_sx[tid] = sx[b * NTOK + i0 + tid];
  else if (tid < 256)  s_sy[tid - 128] = sy[b * NTOK + j0 + (tid - 128)];
  __syncthreads();

  // ---------------- compute: 8 waves in 2x4, each 64x32 ---------------------
  const int l  = tid & 63;
  const int wm = (w >> 2) * 64;
  const int wn = (w & 3) * 32;
  const int lr = l & 15;   // fragment row/col within 16
  const int lg = l >> 4;   // k-group 0..3

  f32x4 acc[4][2] = {};
#pragma unroll
  for (int ks = 0; ks < 4; ++ks) {
    bf16x8 af[4], bv[2];
    const int o = ks * 4 + lg;           // 16B slot (8 k's)
#pragma unroll
    for (int mf = 0; mf < 4; ++mf) {
      const int n = wm + mf * 16 + lr;
      const int slot = o ^ (n & 15) ^ ((n >> 4) & 3);
      af[mf] = *(const bf16x8*)(smA + n * 256 + slot * 16);
    }
#pragma unroll
    for (int nf = 0; nf < 2; ++nf) {
      const int n = wn + nf * 16 + lr;
      const int slot = o ^ (n & 15) ^ ((n >> 4) & 3);
      bv[nf] = *(const bf16x8*)(smB + n * 256 + slot * 16);
    }
#pragma unroll
    for (int mf = 0; mf < 4; ++mf)
#pragma unroll
      for (int nf = 0; nf < 2; ++nf)
        acc[mf][nf] = __builtin_amdgcn_mfma_f32_16x16x32_bf16(
            af[mf], bv[nf], acc[mf][nf], 0, 0, 0);
  }

  // ---------------- epilogue: P = sx[i] + sy[j] - 2*zz, nontemporal stores --
  float srow[4][4], scol[2];
#pragma unroll
  for (int mf = 0; mf < 4; ++mf)
#pragma unroll
    for (int r = 0; r < 4; ++r) srow[mf][r] = s_sx[wm + mf * 16 + lg * 4 + r];
#pragma unroll
  for (int nf = 0; nf < 2; ++nf) scol[nf] = s_sy[wn + nf * 16 + lr];

#pragma unroll
  for (int mf = 0; mf < 4; ++mf)
#pragma unroll
    for (int nf = 0; nf < 2; ++nf)
#pragma unroll
      for (int r = 0; r < 4; ++r) {
        const int row = wm + mf * 16 + lg * 4 + r;   // C/D layout (m89)
        const int col = wn + nf * 16 + lr;
        const float vv = srow[mf][r] + scol[nf] - 2.0f * acc[mf][nf][r];
        __builtin_nontemporal_store(
            vv, out + ((size_t)b * NTOK + (i0 + row)) * NTOK + j0 + col);
      }
}

extern "C" void kernel_launch(void* const* d_in, const int* in_sizes, int n_in,
                              void* d_out, int out_size, void* d_ws, size_t ws_size,
                              hipStream_t stream) {
  (void)in_sizes; (void)n_in; (void)out_size; (void)ws_size;
  const float* x = (const float*)d_in[0];
  const float* y = (const float*)d_in[1];
  float* out = (float*)d_out;
  float* sx = (float*)d_ws;              // 8*2304 fp32
  float* sy = sx + 8 * NTOK;             // 8*2304 fp32 (total 147,456 B of ws)

  dim3 gp(NTOK / 64, 8, 2);
  pwd_prep_norms<<<gp, dim3(256), 0, stream>>>(x, y, sx, sy);

  dim3 gg(18 * 18 * 8);
  pwd_gemm<<<gg, dim3(512), 0, stream>>>(x, y, sx, sy, out);
}